// Round 10
// baseline (314.371 us; speedup 1.0000x reference)
//
#include <hip/hip_runtime.h>
#include <hip/hip_fp16.h>
#include <type_traits>

#define N_NODES 50000
#define N_EDGES 800000
#define WIN_BITS 9
#define WIN 512
#define NBUK ((N_NODES + WIN - 1) / WIN)   // 98
#define BCAP 16384

typedef _Float16 half8 __attribute__((ext_vector_type(8)));
typedef float floatx4 __attribute__((ext_vector_type(4)));

// ---------------------------------------------------------------------------
// P0: bucket edges by destination window. Packed entry: (src << 9) | (dst & 511)
// ---------------------------------------------------------------------------
__global__ __launch_bounds__(256) void p0_bucket(const int* __restrict__ ei,
                                                 int* __restrict__ gcur,
                                                 unsigned* __restrict__ arena, int E) {
    __shared__ int lcnt[NBUK];
    __shared__ int lbase[NBUK];
    int tid = threadIdx.x;
    int chunk = (E + gridDim.x - 1) / gridDim.x;
    int e0 = blockIdx.x * chunk;
    int e1 = e0 + chunk; if (e1 > E) e1 = E;
    for (int b = tid; b < NBUK; b += 256) lcnt[b] = 0;
    __syncthreads();
    for (int e = e0 + tid; e < e1; e += 256) {
        int dst = ei[E + e];
        atomicAdd(&lcnt[dst >> WIN_BITS], 1);
    }
    __syncthreads();
    for (int b = tid; b < NBUK; b += 256) {
        lbase[b] = atomicAdd(&gcur[b], lcnt[b]);
        lcnt[b] = 0;
    }
    __syncthreads();
    for (int e = e0 + tid; e < e1; e += 256) {
        int dst = ei[E + e];
        int src = ei[e];
        int b = dst >> WIN_BITS;
        int pos = lbase[b] + atomicAdd(&lcnt[b], 1);
        if (pos < BCAP)
            arena[(size_t)b * BCAP + pos] = ((unsigned)src << WIN_BITS) | (unsigned)(dst & (WIN - 1));
    }
}

// ---------------------------------------------------------------------------
// Scan bucket totals (gcur, 98 values) -> exclusive bucket offsets. 1 block.
// ---------------------------------------------------------------------------
__global__ void scan_buckets(const int* __restrict__ gcur, int* __restrict__ bukoff,
                             int* __restrict__ offsets, int n, int total) {
    __shared__ int s[128];
    int t = threadIdx.x;
    int v = (t < NBUK) ? gcur[t] : 0;
    s[t] = v;
    __syncthreads();
    for (int off = 1; off < 128; off <<= 1) {
        int u = (t >= off) ? s[t - off] : 0;
        __syncthreads();
        s[t] += u;
        __syncthreads();
    }
    if (t < NBUK) bukoff[t] = s[t] - v;
    if (t == 0) offsets[n] = total;
}

// ---------------------------------------------------------------------------
// P1: per-bucket histogram + intra-bucket scan -> offsets, dinv. One pass.
// ---------------------------------------------------------------------------
__global__ __launch_bounds__(256) void p1_count_scan(const unsigned* __restrict__ arena,
                                                     const int* __restrict__ gcur,
                                                     const int* __restrict__ bukoff,
                                                     int* __restrict__ offsets,
                                                     float* __restrict__ dinv, int n) {
    __shared__ int cnt[WIN];
    __shared__ int sbuf[256];
    int b = blockIdx.x, tid = threadIdx.x;
    cnt[tid] = 0; cnt[tid + 256] = 0;
    __syncthreads();
    int m = gcur[b]; if (m > BCAP) m = BCAP;
    const unsigned* a = arena + (size_t)b * BCAP;
    for (int i = tid; i < m; i += 256) atomicAdd(&cnt[a[i] & (WIN - 1)], 1);
    __syncthreads();
    int j0 = tid * 2;
    int a0 = cnt[j0], a1 = cnt[j0 + 1];
    int ts = a0 + a1;
    sbuf[tid] = ts;
    __syncthreads();
    for (int off = 1; off < 256; off <<= 1) {
        int u = (tid >= off) ? sbuf[tid - off] : 0;
        __syncthreads();
        sbuf[tid] += u;
        __syncthreads();
    }
    int pre = sbuf[tid] - ts;
    int base = b << WIN_BITS;
    int o0 = bukoff[b] + pre, o1 = o0 + a0;
    int d0 = base + j0;
    if (d0 + 1 < n) {
        *(int2*)&offsets[d0] = make_int2(o0, o1);
        *(float2*)&dinv[d0] = make_float2(rsqrtf((float)(a0 + 1)), rsqrtf((float)(a1 + 1)));
    } else if (d0 < n) {
        offsets[d0] = o0;
        dinv[d0] = rsqrtf((float)(a0 + 1));
    }
}

// ---------------------------------------------------------------------------
// P2: per-bucket CSR fill.
// ---------------------------------------------------------------------------
__global__ __launch_bounds__(256) void p2_fill(const unsigned* __restrict__ arena,
                                               const int* __restrict__ gcur,
                                               const int* __restrict__ offsets,
                                               int* __restrict__ csr_src, int n) {
    __shared__ int cur[WIN];
    int b = blockIdx.x, tid = threadIdx.x;
    int base = b << WIN_BITS;
    for (int j = tid; j < WIN; j += 256) {
        int d = base + j;
        cur[j] = (d < n) ? offsets[d] : 0;
    }
    __syncthreads();
    int m = gcur[b]; if (m > BCAP) m = BCAP;
    const unsigned* a = arena + (size_t)b * BCAP;
    for (int i = tid; i < m; i += 256) {
        unsigned e = a[i];
        int pos = atomicAdd(&cur[e & (WIN - 1)], 1);
        csr_src[pos] = (int)(e >> WIN_BITS);
    }
}

// ---------------------------------------------------------------------------
// MFMA GEMM (layer 1): h[i][j] = fp16( (x[i,:] @ W[:,j]) * dinv[i] ), FI=128.
// A-frag = W-tile (m=outcol), B-frag = x (n=node).
// ---------------------------------------------------------------------------
template<int FO, typename InT>
__global__ __launch_bounds__(256) void gemm_mfma_kernel(
        const InT* __restrict__ x, const float* __restrict__ W,
        const float* __restrict__ dinv, __half* __restrict__ h, int n) {
    constexpr int NT = FO / 16;
    __shared__ _Float16 wlds[16 * FO * 8];

    int tid = threadIdx.x;
    constexpr int G = 16 * FO;
    for (int it = 0; it < G / 256; ++it) {
        int g = tid + it * 256;
        int col = g % FO;
        int sq = g / FO;
        int k0 = sq * 8;
        half8 hv;
        #pragma unroll
        for (int j = 0; j < 8; ++j)
            hv[j] = (_Float16)W[(size_t)(k0 + j) * FO + col];
        *(half8*)&wlds[(size_t)g * 8] = hv;
    }
    __syncthreads();

    int ln = tid & 15;
    int q  = (tid >> 4) & 3;
    int w  = tid >> 6;
    int node = blockIdx.x * 64 + w * 16 + ln;
    int nodec = node < n ? node : n - 1;
    const InT* xrow = x + (size_t)nodec * 128;

    floatx4 acc[NT];
    #pragma unroll
    for (int t = 0; t < NT; ++t) acc[t] = (floatx4){0.f, 0.f, 0.f, 0.f};

    #pragma unroll
    for (int s = 0; s < 4; ++s) {
        half8 xf;
        if constexpr (std::is_same_v<InT, float>) {
            const float* xp = xrow + s * 32 + q * 8;
            float4 a0 = *(const float4*)xp;
            float4 a1 = *(const float4*)(xp + 4);
            xf[0] = (_Float16)a0.x; xf[1] = (_Float16)a0.y;
            xf[2] = (_Float16)a0.z; xf[3] = (_Float16)a0.w;
            xf[4] = (_Float16)a1.x; xf[5] = (_Float16)a1.y;
            xf[6] = (_Float16)a1.z; xf[7] = (_Float16)a1.w;
        } else {
            xf = *(const half8*)(xrow + s * 32 + q * 8);
        }
        int sq = s * 4 + q;
        #pragma unroll
        for (int t = 0; t < NT; ++t) {
            half8 wf = *(const half8*)&wlds[(size_t)(sq * FO + t * 16 + ln) * 8];
            acc[t] = __builtin_amdgcn_mfma_f32_16x16x32_f16(wf, xf, acc[t], 0, 0, 0);
        }
    }

    if (node < n) {
        float dv = dinv[node];
        __half* hrow = h + (size_t)node * FO;
        #pragma unroll
        for (int t = 0; t < NT; ++t) {
            __half2 p[2];
            p[0] = __float22half2_rn(make_float2(acc[t][0] * dv, acc[t][1] * dv));
            p[1] = __float22half2_rn(make_float2(acc[t][2] * dv, acc[t][3] * dv));
            *(uint2*)&hrow[t * 16 + q * 4] = *(const uint2*)p;
        }
    }
}

// ---------------------------------------------------------------------------
// Fused agg_i + gemm_{i+1}: block = 64 nodes, 512 threads (8 waves).
// Phase A: wave w aggregates nodes w*8..w*8+8 (flat gather, relu'd activation
// -> LDS, padded stride 136 halfs). Phase B: MFMA vs LDS-staged W, epilogue
// scales by dinv and writes fp16 h for the next gather. Activation never
// touches global memory.
// ---------------------------------------------------------------------------
template<int FO>
__global__ __launch_bounds__(512) void fused_agg_gemm(
        const __half2* __restrict__ hin, const int* __restrict__ offsets,
        const int* __restrict__ csr_src, const float* __restrict__ dinv,
        const float* __restrict__ bias, const float* __restrict__ W,
        __half* __restrict__ hout, int n) {
    constexpr int NT  = FO / 16;
    constexpr int TPW = NT / 2;                  // tiles per wave (cg in {0,1})
    __shared__ _Float16 wlds[16 * FO * 8];       // 32 KB / 16 KB
    __shared__ _Float16 aggL[64 * 136];          // 17.4 KB, padded stride

    int tid = threadIdx.x;
    // ---- stage W (fragment order), overlaps with agg phase ----
    constexpr int G = 16 * FO;
    for (int it = 0; it < G / 512; ++it) {
        int g = tid + it * 512;
        int col = g % FO;
        int sq = g / FO;
        int k0 = sq * 8;
        half8 hv;
        #pragma unroll
        for (int j = 0; j < 8; ++j)
            hv[j] = (_Float16)W[(size_t)(k0 + j) * FO + col];
        *(half8*)&wlds[(size_t)g * 8] = hv;
    }

    // ---- phase A: aggregate 8 nodes per wave ----
    int w = tid >> 6;
    int lane = tid & 63;
    float2 bb = ((const float2*)bias)[lane];
    __half2* aggRow = (__half2*)aggL;
    for (int ii = 0; ii < 8; ++ii) {
        int c = blockIdx.x * 64 + w * 8 + ii;
        if (c >= n) break;
        c = __builtin_amdgcn_readfirstlane(c);
        float2 acc = __half22float2(hin[(size_t)c * 64 + lane]);   // self loop
        int s = offsets[c], e = offsets[c + 1];
        int i = s;
        for (; i + 3 < e; i += 4) {
            int s0 = csr_src[i], s1 = csr_src[i + 1], s2 = csr_src[i + 2], s3 = csr_src[i + 3];
            float2 f0 = __half22float2(hin[(size_t)s0 * 64 + lane]);
            float2 f1 = __half22float2(hin[(size_t)s1 * 64 + lane]);
            float2 f2 = __half22float2(hin[(size_t)s2 * 64 + lane]);
            float2 f3 = __half22float2(hin[(size_t)s3 * 64 + lane]);
            acc.x += f0.x + f1.x; acc.y += f0.y + f1.y;
            acc.x += f2.x + f3.x; acc.y += f2.y + f3.y;
        }
        for (; i < e; ++i) {
            float2 f = __half22float2(hin[(size_t)csr_src[i] * 64 + lane]);
            acc.x += f.x; acc.y += f.y;
        }
        float dc = dinv[c];
        float vx = fmaxf(fmaf(acc.x, dc, bb.x), 0.0f);   // relu activation
        float vy = fmaxf(fmaf(acc.y, dc, bb.y), 0.0f);
        aggRow[(size_t)(w * 8 + ii) * 68 + lane] = __float22half2_rn(make_float2(vx, vy));
    }
    __syncthreads();

    // ---- phase B: MFMA. wave = (nodegroup ng 0..3, colgroup cg 0..1) ----
    int ng = w & 3, cg = w >> 2;
    int ln = tid & 15;
    int q  = (tid >> 4) & 3;
    int nl = ng * 16 + ln;                       // node local 0..63
    int node = blockIdx.x * 64 + nl;

    floatx4 acc[TPW];
    #pragma unroll
    for (int t = 0; t < TPW; ++t) acc[t] = (floatx4){0.f, 0.f, 0.f, 0.f};

    #pragma unroll
    for (int s = 0; s < 4; ++s) {
        half8 xf = *(const half8*)&aggL[(size_t)nl * 136 + s * 32 + q * 8];
        int sq = s * 4 + q;
        #pragma unroll
        for (int t = 0; t < TPW; ++t) {
            int T = cg * TPW + t;
            half8 wf = *(const half8*)&wlds[(size_t)(sq * FO + T * 16 + ln) * 8];
            acc[t] = __builtin_amdgcn_mfma_f32_16x16x32_f16(wf, xf, acc[t], 0, 0, 0);
        }
    }

    if (node < n) {
        float dv = dinv[node];
        __half* hrow = hout + (size_t)node * FO;
        #pragma unroll
        for (int t = 0; t < TPW; ++t) {
            int T = cg * TPW + t;
            __half2 p[2];
            p[0] = __float22half2_rn(make_float2(acc[t][0] * dv, acc[t][1] * dv));
            p[1] = __float22half2_rn(make_float2(acc[t][2] * dv, acc[t][3] * dv));
            *(uint2*)&hrow[T * 16 + q * 4] = *(const uint2*)p;
        }
    }
}

// ---------------------------------------------------------------------------
// Final aggregation (FO=64): wave = 2 halves x 32 lanes, fp32 out to d_out.
// ---------------------------------------------------------------------------
__global__ __launch_bounds__(256) void agg64_kernel(
        const __half2* __restrict__ h2, const int* __restrict__ offsets,
        const int* __restrict__ csr_src, const float* __restrict__ dinv,
        const float* __restrict__ bias, float* __restrict__ out, int n) {
    int lane = threadIdx.x & 63;
    int hf = lane >> 5, sl = lane & 31;
    int c = (blockIdx.x << 2) + (threadIdx.x >> 6);
    if (c >= n) return;
    c = __builtin_amdgcn_readfirstlane(c);
    float2 acc = make_float2(0.0f, 0.0f);
    if (hf == 0) acc = __half22float2(h2[(size_t)c * 32 + sl]);   // self loop
    int s = offsets[c], e = offsets[c + 1];
    int i = s;
    for (; i + 3 < e; i += 4) {
        int sa = csr_src[i + hf];
        int sb = csr_src[i + 2 + hf];
        float2 fa = __half22float2(h2[(size_t)sa * 32 + sl]);
        float2 fb = __half22float2(h2[(size_t)sb * 32 + sl]);
        acc.x += fa.x + fb.x; acc.y += fa.y + fb.y;
    }
    for (; i + 1 < e; i += 2) {
        int sa = csr_src[i + hf];
        float2 fa = __half22float2(h2[(size_t)sa * 32 + sl]);
        acc.x += fa.x; acc.y += fa.y;
    }
    if (i < e && hf == 0) {
        float2 fa = __half22float2(h2[(size_t)csr_src[i] * 32 + sl]);
        acc.x += fa.x; acc.y += fa.y;
    }
    acc.x += __shfl_xor(acc.x, 32);
    acc.y += __shfl_xor(acc.y, 32);
    if (hf == 0) {
        float dc = dinv[c];
        float2 bb = ((const float2*)bias)[sl];
        float2 o;
        o.x = fmaf(acc.x, dc, bb.x);
        o.y = fmaf(acc.y, dc, bb.y);
        ((float2*)out)[(size_t)c * 32 + sl] = o;
    }
}

// ---------------------------------------------------------------------------

extern "C" void kernel_launch(void* const* d_in, const int* in_sizes, int n_in,
                              void* d_out, int out_size, void* d_ws, size_t ws_size,
                              hipStream_t stream) {
    const float* x  = (const float*)d_in[0];
    const int*   ei = (const int*)  d_in[1];
    const float* W1 = (const float*)d_in[2];
    const float* b1 = (const float*)d_in[3];
    const float* W2 = (const float*)d_in[4];
    const float* b2 = (const float*)d_in[5];
    const float* W3 = (const float*)d_in[6];
    const float* b3 = (const float*)d_in[7];
    const float* W4 = (const float*)d_in[8];
    const float* b4 = (const float*)d_in[9];

    const int N = N_NODES, E = N_EDGES;

    char* p = (char*)d_ws;
    auto carve = [&](size_t bytes) {
        char* q = p;
        p += (bytes + 255) & ~(size_t)255;
        return (void*)q;
    };
    int*      offsets  = (int*)     carve((size_t)(N + 1) * 4);
    int*      csr_src  = (int*)     carve((size_t)E * 4);
    float*    dinv     = (float*)   carve((size_t)N * 4);
    int*      gcur     = (int*)     carve((size_t)NBUK * 4);
    int*      bukoff   = (int*)     carve((size_t)NBUK * 4);
    unsigned* arena    = (unsigned*)carve((size_t)NBUK * BCAP * 4);
    __half*   A1       = (__half*)  carve((size_t)N * 128 * 2);
    __half*   A2       = (__half*)  carve((size_t)N * 128 * 2);

    // ---- graph build (5 dispatches) ----
    hipMemsetAsync(gcur, 0, (size_t)NBUK * 4, stream);
    p0_bucket<<<512, 256, 0, stream>>>(ei, gcur, arena, E);
    scan_buckets<<<1, 128, 0, stream>>>(gcur, bukoff, offsets, N, E);
    p1_count_scan<<<NBUK, 256, 0, stream>>>(arena, gcur, bukoff, offsets, dinv, N);
    p2_fill<<<NBUK, 256, 0, stream>>>(arena, gcur, offsets, csr_src, N);

    // ---- layers (5 dispatches) ----
    const int nb64 = (N + 63) / 64;    // 782

    gemm_mfma_kernel<128, float><<<nb64, 256, 0, stream>>>(x, W1, dinv, A1, N);
    fused_agg_gemm<128><<<nb64, 512, 0, stream>>>((const __half2*)A1, offsets, csr_src, dinv, b1, W2, A2, N);
    fused_agg_gemm<128><<<nb64, 512, 0, stream>>>((const __half2*)A2, offsets, csr_src, dinv, b2, W3, A1, N);
    fused_agg_gemm<64><<<nb64, 512, 0, stream>>>((const __half2*)A1, offsets, csr_src, dinv, b3, W4, A2, N);
    agg64_kernel<<<(N + 3) / 4, 256, 0, stream>>>((const __half2*)A2, offsets, csr_src, dinv, b4, (float*)d_out, N);
}

// Round 12
// 285.099 us; speedup vs baseline: 1.1027x; 1.1027x over previous
//
#include <hip/hip_runtime.h>
#include <hip/hip_fp16.h>
#include <type_traits>

#define N_NODES 50000
#define N_EDGES 800000
#define WIN_BITS 9
#define WIN 512
#define NBUK ((N_NODES + WIN - 1) / WIN)   // 98
#define BCAP 16384

typedef _Float16 half8 __attribute__((ext_vector_type(8)));
typedef float floatx4 __attribute__((ext_vector_type(4)));

// ---------------------------------------------------------------------------
// P0: bucket edges by destination window. Packed entry: (src << 9) | (dst & 511)
// ---------------------------------------------------------------------------
__global__ __launch_bounds__(256) void p0_bucket(const int* __restrict__ ei,
                                                 int* __restrict__ gcur,
                                                 unsigned* __restrict__ arena, int E) {
    __shared__ int lcnt[NBUK];
    __shared__ int lbase[NBUK];
    int tid = threadIdx.x;
    int chunk = (E + gridDim.x - 1) / gridDim.x;
    int e0 = blockIdx.x * chunk;
    int e1 = e0 + chunk; if (e1 > E) e1 = E;
    for (int b = tid; b < NBUK; b += 256) lcnt[b] = 0;
    __syncthreads();
    for (int e = e0 + tid; e < e1; e += 256) {
        int dst = ei[E + e];
        atomicAdd(&lcnt[dst >> WIN_BITS], 1);
    }
    __syncthreads();
    for (int b = tid; b < NBUK; b += 256) {
        lbase[b] = atomicAdd(&gcur[b], lcnt[b]);
        lcnt[b] = 0;
    }
    __syncthreads();
    for (int e = e0 + tid; e < e1; e += 256) {
        int dst = ei[E + e];
        int src = ei[e];
        int b = dst >> WIN_BITS;
        int pos = lbase[b] + atomicAdd(&lcnt[b], 1);
        if (pos < BCAP)
            arena[(size_t)b * BCAP + pos] = ((unsigned)src << WIN_BITS) | (unsigned)(dst & (WIN - 1));
    }
}

// ---------------------------------------------------------------------------
// Scan bucket totals (gcur, 98 values) -> exclusive bucket offsets. 1 block.
// ---------------------------------------------------------------------------
__global__ void scan_buckets(const int* __restrict__ gcur, int* __restrict__ bukoff,
                             int* __restrict__ offsets, int n, int total) {
    __shared__ int s[128];
    int t = threadIdx.x;
    int v = (t < NBUK) ? gcur[t] : 0;
    s[t] = v;
    __syncthreads();
    for (int off = 1; off < 128; off <<= 1) {
        int u = (t >= off) ? s[t - off] : 0;
        __syncthreads();
        s[t] += u;
        __syncthreads();
    }
    if (t < NBUK) bukoff[t] = s[t] - v;
    if (t == 0) offsets[n] = total;
}

// ---------------------------------------------------------------------------
// P1: per-bucket histogram + intra-bucket scan -> offsets, dinv. One pass.
// ---------------------------------------------------------------------------
__global__ __launch_bounds__(256) void p1_count_scan(const unsigned* __restrict__ arena,
                                                     const int* __restrict__ gcur,
                                                     const int* __restrict__ bukoff,
                                                     int* __restrict__ offsets,
                                                     float* __restrict__ dinv, int n) {
    __shared__ int cnt[WIN];
    __shared__ int sbuf[256];
    int b = blockIdx.x, tid = threadIdx.x;
    cnt[tid] = 0; cnt[tid + 256] = 0;
    __syncthreads();
    int m = gcur[b]; if (m > BCAP) m = BCAP;
    const unsigned* a = arena + (size_t)b * BCAP;
    for (int i = tid; i < m; i += 256) atomicAdd(&cnt[a[i] & (WIN - 1)], 1);
    __syncthreads();
    int j0 = tid * 2;
    int a0 = cnt[j0], a1 = cnt[j0 + 1];
    int ts = a0 + a1;
    sbuf[tid] = ts;
    __syncthreads();
    for (int off = 1; off < 256; off <<= 1) {
        int u = (tid >= off) ? sbuf[tid - off] : 0;
        __syncthreads();
        sbuf[tid] += u;
        __syncthreads();
    }
    int pre = sbuf[tid] - ts;
    int base = b << WIN_BITS;
    int o0 = bukoff[b] + pre, o1 = o0 + a0;
    int d0 = base + j0;
    if (d0 + 1 < n) {
        *(int2*)&offsets[d0] = make_int2(o0, o1);
        *(float2*)&dinv[d0] = make_float2(rsqrtf((float)(a0 + 1)), rsqrtf((float)(a1 + 1)));
    } else if (d0 < n) {
        offsets[d0] = o0;
        dinv[d0] = rsqrtf((float)(a0 + 1));
    }
}

// ---------------------------------------------------------------------------
// P2: per-bucket CSR fill.
// ---------------------------------------------------------------------------
__global__ __launch_bounds__(256) void p2_fill(const unsigned* __restrict__ arena,
                                               const int* __restrict__ gcur,
                                               const int* __restrict__ offsets,
                                               int* __restrict__ csr_src, int n) {
    __shared__ int cur[WIN];
    int b = blockIdx.x, tid = threadIdx.x;
    int base = b << WIN_BITS;
    for (int j = tid; j < WIN; j += 256) {
        int d = base + j;
        cur[j] = (d < n) ? offsets[d] : 0;
    }
    __syncthreads();
    int m = gcur[b]; if (m > BCAP) m = BCAP;
    const unsigned* a = arena + (size_t)b * BCAP;
    for (int i = tid; i < m; i += 256) {
        unsigned e = a[i];
        int pos = atomicAdd(&cur[e & (WIN - 1)], 1);
        csr_src[pos] = (int)(e >> WIN_BITS);
    }
}

// ---------------------------------------------------------------------------
// W fp32 -> fp16 fragment-order conversion (one-time, broadcast W).
// Wfrag[(sq*FO + col)*8 + j] = W[(sq*8 + j)*FO + col],  sq in [0,16).
// ---------------------------------------------------------------------------
__global__ void wfrag_kernel(const float* __restrict__ W, _Float16* __restrict__ Wf, int FO) {
    int g = blockIdx.x * 256 + threadIdx.x;
    if (g >= 16 * FO) return;
    int col = g % FO;
    int sq = g / FO;
    int k0 = sq * 8;
    half8 hv;
    #pragma unroll
    for (int j = 0; j < 8; ++j)
        hv[j] = (_Float16)W[(size_t)(k0 + j) * FO + col];
    *(half8*)&Wf[(size_t)g * 8] = hv;
}

// ---------------------------------------------------------------------------
// MFMA GEMM (layer 1): h[i][j] = fp16( (x[i,:] @ W[:,j]) * dinv[i] ), FI=128.
// A-frag = W-tile (m=outcol), B-frag = x (n=node). W staged in LDS (fp32 in).
// ---------------------------------------------------------------------------
template<int FO, typename InT>
__global__ __launch_bounds__(256) void gemm_mfma_kernel(
        const InT* __restrict__ x, const float* __restrict__ W,
        const float* __restrict__ dinv, __half* __restrict__ h, int n) {
    constexpr int NT = FO / 16;
    __shared__ _Float16 wlds[16 * FO * 8];

    int tid = threadIdx.x;
    constexpr int G = 16 * FO;
    for (int it = 0; it < G / 256; ++it) {
        int g = tid + it * 256;
        int col = g % FO;
        int sq = g / FO;
        int k0 = sq * 8;
        half8 hv;
        #pragma unroll
        for (int j = 0; j < 8; ++j)
            hv[j] = (_Float16)W[(size_t)(k0 + j) * FO + col];
        *(half8*)&wlds[(size_t)g * 8] = hv;
    }
    __syncthreads();

    int ln = tid & 15;
    int q  = (tid >> 4) & 3;
    int w  = tid >> 6;
    int node = blockIdx.x * 64 + w * 16 + ln;
    int nodec = node < n ? node : n - 1;
    const InT* xrow = x + (size_t)nodec * 128;

    floatx4 acc[NT];
    #pragma unroll
    for (int t = 0; t < NT; ++t) acc[t] = (floatx4){0.f, 0.f, 0.f, 0.f};

    #pragma unroll
    for (int s = 0; s < 4; ++s) {
        half8 xf;
        if constexpr (std::is_same_v<InT, float>) {
            const float* xp = xrow + s * 32 + q * 8;
            float4 a0 = *(const float4*)xp;
            float4 a1 = *(const float4*)(xp + 4);
            xf[0] = (_Float16)a0.x; xf[1] = (_Float16)a0.y;
            xf[2] = (_Float16)a0.z; xf[3] = (_Float16)a0.w;
            xf[4] = (_Float16)a1.x; xf[5] = (_Float16)a1.y;
            xf[6] = (_Float16)a1.z; xf[7] = (_Float16)a1.w;
        } else {
            xf = *(const half8*)(xrow + s * 32 + q * 8);
        }
        int sq = s * 4 + q;
        #pragma unroll
        for (int t = 0; t < NT; ++t) {
            half8 wf = *(const half8*)&wlds[(size_t)(sq * FO + t * 16 + ln) * 8];
            acc[t] = __builtin_amdgcn_mfma_f32_16x16x32_f16(wf, xf, acc[t], 0, 0, 0);
        }
    }

    if (node < n) {
        float dv = dinv[node];
        __half* hrow = h + (size_t)node * FO;
        #pragma unroll
        for (int t = 0; t < NT; ++t) {
            __half2 p[2];
            p[0] = __float22half2_rn(make_float2(acc[t][0] * dv, acc[t][1] * dv));
            p[1] = __float22half2_rn(make_float2(acc[t][2] * dv, acc[t][3] * dv));
            *(uint2*)&hrow[t * 16 + q * 4] = *(const uint2*)p;
        }
    }
}

// ---------------------------------------------------------------------------
// Fused agg_i + gemm_{i+1}: block = 64 nodes, 512 threads (8 waves).
// Phase A: wave w aggregates nodes w*8..w*8+8 (flat gather, 8 loads in
// flight, relu'd activation -> LDS, padded stride 136 halfs). Phase B: MFMA
// with W-fragments read DIRECTLY from global (fp16 fragment-order Wfrag,
// L1/L2-broadcast) -- no W in LDS, so LDS = 17.4 KB and occupancy is
// wave-slot-limited (4 blocks x 8 waves = 32 waves/CU for the gather phase).
// ---------------------------------------------------------------------------
template<int FO>
__global__ __launch_bounds__(512) void fused_agg_gemm(
        const __half2* __restrict__ hin, const int* __restrict__ offsets,
        const int* __restrict__ csr_src, const float* __restrict__ dinv,
        const float* __restrict__ bias, const _Float16* __restrict__ Wfrag,
        __half* __restrict__ hout, int n) {
    constexpr int NT  = FO / 16;
    constexpr int TPW = NT / 2;                  // tiles per wave (cg in {0,1})
    __shared__ _Float16 aggL[64 * 136];          // 17.4 KB, padded stride

    int tid = threadIdx.x;

    // ---- phase A: aggregate 8 nodes per wave ----
    int w = tid >> 6;
    int lane = tid & 63;
    float2 bb = ((const float2*)bias)[lane];
    __half2* aggRow = (__half2*)aggL;
    for (int ii = 0; ii < 8; ++ii) {
        int c = blockIdx.x * 64 + w * 8 + ii;
        if (c >= n) break;
        c = __builtin_amdgcn_readfirstlane(c);
        float2 acc = __half22float2(hin[(size_t)c * 64 + lane]);   // self loop
        int s = offsets[c], e = offsets[c + 1];
        int i = s;
        for (; i + 7 < e; i += 8) {
            int s0 = csr_src[i],     s1 = csr_src[i + 1], s2 = csr_src[i + 2], s3 = csr_src[i + 3];
            int s4 = csr_src[i + 4], s5 = csr_src[i + 5], s6 = csr_src[i + 6], s7 = csr_src[i + 7];
            float2 f0 = __half22float2(hin[(size_t)s0 * 64 + lane]);
            float2 f1 = __half22float2(hin[(size_t)s1 * 64 + lane]);
            float2 f2 = __half22float2(hin[(size_t)s2 * 64 + lane]);
            float2 f3 = __half22float2(hin[(size_t)s3 * 64 + lane]);
            float2 f4 = __half22float2(hin[(size_t)s4 * 64 + lane]);
            float2 f5 = __half22float2(hin[(size_t)s5 * 64 + lane]);
            float2 f6 = __half22float2(hin[(size_t)s6 * 64 + lane]);
            float2 f7 = __half22float2(hin[(size_t)s7 * 64 + lane]);
            acc.x += (f0.x + f1.x) + (f2.x + f3.x) + (f4.x + f5.x) + (f6.x + f7.x);
            acc.y += (f0.y + f1.y) + (f2.y + f3.y) + (f4.y + f5.y) + (f6.y + f7.y);
        }
        for (; i + 3 < e; i += 4) {
            int s0 = csr_src[i], s1 = csr_src[i + 1], s2 = csr_src[i + 2], s3 = csr_src[i + 3];
            float2 f0 = __half22float2(hin[(size_t)s0 * 64 + lane]);
            float2 f1 = __half22float2(hin[(size_t)s1 * 64 + lane]);
            float2 f2 = __half22float2(hin[(size_t)s2 * 64 + lane]);
            float2 f3 = __half22float2(hin[(size_t)s3 * 64 + lane]);
            acc.x += (f0.x + f1.x) + (f2.x + f3.x);
            acc.y += (f0.y + f1.y) + (f2.y + f3.y);
        }
        for (; i < e; ++i) {
            float2 f = __half22float2(hin[(size_t)csr_src[i] * 64 + lane]);
            acc.x += f.x; acc.y += f.y;
        }
        float dc = dinv[c];
        float vx = fmaxf(fmaf(acc.x, dc, bb.x), 0.0f);   // relu activation
        float vy = fmaxf(fmaf(acc.y, dc, bb.y), 0.0f);
        aggRow[(size_t)(w * 8 + ii) * 68 + lane] = __float22half2_rn(make_float2(vx, vy));
    }
    __syncthreads();

    // ---- phase B: MFMA. wave = (nodegroup ng 0..3, colgroup cg 0..1) ----
    int ng = w & 3, cg = w >> 2;
    int ln = tid & 15;
    int q  = (tid >> 4) & 3;
    int nl = ng * 16 + ln;                       // node local 0..63
    int node = blockIdx.x * 64 + nl;

    floatx4 acc[TPW];
    #pragma unroll
    for (int t = 0; t < TPW; ++t) acc[t] = (floatx4){0.f, 0.f, 0.f, 0.f};

    #pragma unroll
    for (int s = 0; s < 4; ++s) {
        half8 xf = *(const half8*)&aggL[(size_t)nl * 136 + s * 32 + q * 8];
        int sq = s * 4 + q;
        #pragma unroll
        for (int t = 0; t < TPW; ++t) {
            int T = cg * TPW + t;
            half8 wf = *(const half8*)&Wfrag[(size_t)(sq * FO + T * 16 + ln) * 8];
            acc[t] = __builtin_amdgcn_mfma_f32_16x16x32_f16(wf, xf, acc[t], 0, 0, 0);
        }
    }

    if (node < n) {
        float dv = dinv[node];
        __half* hrow = hout + (size_t)node * FO;
        #pragma unroll
        for (int t = 0; t < TPW; ++t) {
            int T = cg * TPW + t;
            __half2 p[2];
            p[0] = __float22half2_rn(make_float2(acc[t][0] * dv, acc[t][1] * dv));
            p[1] = __float22half2_rn(make_float2(acc[t][2] * dv, acc[t][3] * dv));
            *(uint2*)&hrow[T * 16 + q * 4] = *(const uint2*)p;
        }
    }
}

// ---------------------------------------------------------------------------
// Final aggregation (FO=64): wave = 2 halves x 32 lanes, fp32 out to d_out.
// ---------------------------------------------------------------------------
__global__ __launch_bounds__(256) void agg64_kernel(
        const __half2* __restrict__ h2, const int* __restrict__ offsets,
        const int* __restrict__ csr_src, const float* __restrict__ dinv,
        const float* __restrict__ bias, float* __restrict__ out, int n) {
    int lane = threadIdx.x & 63;
    int hf = lane >> 5, sl = lane & 31;
    int c = (blockIdx.x << 2) + (threadIdx.x >> 6);
    if (c >= n) return;
    c = __builtin_amdgcn_readfirstlane(c);
    float2 acc = make_float2(0.0f, 0.0f);
    if (hf == 0) acc = __half22float2(h2[(size_t)c * 32 + sl]);   // self loop
    int s = offsets[c], e = offsets[c + 1];
    int i = s;
    for (; i + 3 < e; i += 4) {
        int sa = csr_src[i + hf];
        int sb = csr_src[i + 2 + hf];
        float2 fa = __half22float2(h2[(size_t)sa * 32 + sl]);
        float2 fb = __half22float2(h2[(size_t)sb * 32 + sl]);
        acc.x += fa.x + fb.x; acc.y += fa.y + fb.y;
    }
    for (; i + 1 < e; i += 2) {
        int sa = csr_src[i + hf];
        float2 fa = __half22float2(h2[(size_t)sa * 32 + sl]);
        acc.x += fa.x; acc.y += fa.y;
    }
    if (i < e && hf == 0) {
        float2 fa = __half22float2(h2[(size_t)csr_src[i] * 32 + sl]);
        acc.x += fa.x; acc.y += fa.y;
    }
    acc.x += __shfl_xor(acc.x, 32);
    acc.y += __shfl_xor(acc.y, 32);
    if (hf == 0) {
        float dc = dinv[c];
        float2 bb = ((const float2*)bias)[sl];
        float2 o;
        o.x = fmaf(acc.x, dc, bb.x);
        o.y = fmaf(acc.y, dc, bb.y);
        ((float2*)out)[(size_t)c * 32 + sl] = o;
    }
}

// ---------------------------------------------------------------------------

extern "C" void kernel_launch(void* const* d_in, const int* in_sizes, int n_in,
                              void* d_out, int out_size, void* d_ws, size_t ws_size,
                              hipStream_t stream) {
    const float* x  = (const float*)d_in[0];
    const int*   ei = (const int*)  d_in[1];
    const float* W1 = (const float*)d_in[2];
    const float* b1 = (const float*)d_in[3];
    const float* W2 = (const float*)d_in[4];
    const float* b2 = (const float*)d_in[5];
    const float* W3 = (const float*)d_in[6];
    const float* b3 = (const float*)d_in[7];
    const float* W4 = (const float*)d_in[8];
    const float* b4 = (const float*)d_in[9];

    const int N = N_NODES, E = N_EDGES;

    char* p = (char*)d_ws;
    auto carve = [&](size_t bytes) {
        char* q = p;
        p += (bytes + 255) & ~(size_t)255;
        return (void*)q;
    };
    int*       offsets = (int*)      carve((size_t)(N + 1) * 4);
    int*       csr_src = (int*)      carve((size_t)E * 4);
    float*     dinv    = (float*)    carve((size_t)N * 4);
    int*       gcur    = (int*)      carve((size_t)NBUK * 4);
    int*       bukoff  = (int*)      carve((size_t)NBUK * 4);
    unsigned*  arena   = (unsigned*) carve((size_t)NBUK * BCAP * 4);
    _Float16*  Wf2     = (_Float16*) carve((size_t)16 * 128 * 8 * 2);   // 32 KB
    _Float16*  Wf3     = (_Float16*) carve((size_t)16 * 128 * 8 * 2);
    _Float16*  Wf4     = (_Float16*) carve((size_t)16 * 64 * 8 * 2);    // 16 KB
    __half*    A1      = (__half*)   carve((size_t)N * 128 * 2);
    __half*    A2      = (__half*)   carve((size_t)N * 128 * 2);

    // ---- graph build + W conversion ----
    hipMemsetAsync(gcur, 0, (size_t)NBUK * 4, stream);
    p0_bucket<<<512, 256, 0, stream>>>(ei, gcur, arena, E);
    scan_buckets<<<1, 128, 0, stream>>>(gcur, bukoff, offsets, N, E);
    p1_count_scan<<<NBUK, 256, 0, stream>>>(arena, gcur, bukoff, offsets, dinv, N);
    p2_fill<<<NBUK, 256, 0, stream>>>(arena, gcur, offsets, csr_src, N);
    wfrag_kernel<<<8, 256, 0, stream>>>(W2, Wf2, 128);
    wfrag_kernel<<<8, 256, 0, stream>>>(W3, Wf3, 128);
    wfrag_kernel<<<4, 256, 0, stream>>>(W4, Wf4, 64);

    // ---- layers ----
    const int nb64 = (N + 63) / 64;    // 782

    gemm_mfma_kernel<128, float><<<nb64, 256, 0, stream>>>(x, W1, dinv, A1, N);
    fused_agg_gemm<128><<<nb64, 512, 0, stream>>>((const __half2*)A1, offsets, csr_src, dinv, b1, Wf2, A2, N);
    fused_agg_gemm<128><<<nb64, 512, 0, stream>>>((const __half2*)A2, offsets, csr_src, dinv, b2, Wf3, A1, N);
    fused_agg_gemm<64><<<nb64, 512, 0, stream>>>((const __half2*)A1, offsets, csr_src, dinv, b3, Wf4, A2, N);
    agg64_kernel<<<(N + 3) / 4, 256, 0, stream>>>((const __half2*)A2, offsets, csr_src, dinv, b4, (float*)d_out, N);
}

// Round 13
// 280.797 us; speedup vs baseline: 1.1196x; 1.0153x over previous
//
#include <hip/hip_runtime.h>
#include <hip/hip_fp16.h>
#include <type_traits>

#define N_NODES 50000
#define N_EDGES 800000
#define WIN_BITS 9
#define WIN 512
#define NBUK ((N_NODES + WIN - 1) / WIN)   // 98
#define BCAP 16384

typedef _Float16 half8 __attribute__((ext_vector_type(8)));
typedef float floatx4 __attribute__((ext_vector_type(4)));

__device__ inline void acc8(float* a, half8 v) {
    const __half2* p = (const __half2*)&v;
    float2 f0 = __half22float2(p[0]);
    float2 f1 = __half22float2(p[1]);
    float2 f2 = __half22float2(p[2]);
    float2 f3 = __half22float2(p[3]);
    a[0] += f0.x; a[1] += f0.y; a[2] += f1.x; a[3] += f1.y;
    a[4] += f2.x; a[5] += f2.y; a[6] += f3.x; a[7] += f3.y;
}

// ---------------------------------------------------------------------------
// P0: bucket edges by destination window. Packed entry: (src << 9) | (dst & 511)
// ---------------------------------------------------------------------------
__global__ __launch_bounds__(256) void p0_bucket(const int* __restrict__ ei,
                                                 int* __restrict__ gcur,
                                                 unsigned* __restrict__ arena, int E) {
    __shared__ int lcnt[NBUK];
    __shared__ int lbase[NBUK];
    int tid = threadIdx.x;
    int chunk = (E + gridDim.x - 1) / gridDim.x;
    int e0 = blockIdx.x * chunk;
    int e1 = e0 + chunk; if (e1 > E) e1 = E;
    for (int b = tid; b < NBUK; b += 256) lcnt[b] = 0;
    __syncthreads();
    for (int e = e0 + tid; e < e1; e += 256) {
        int dst = ei[E + e];
        atomicAdd(&lcnt[dst >> WIN_BITS], 1);
    }
    __syncthreads();
    for (int b = tid; b < NBUK; b += 256) {
        lbase[b] = atomicAdd(&gcur[b], lcnt[b]);
        lcnt[b] = 0;
    }
    __syncthreads();
    for (int e = e0 + tid; e < e1; e += 256) {
        int dst = ei[E + e];
        int src = ei[e];
        int b = dst >> WIN_BITS;
        int pos = lbase[b] + atomicAdd(&lcnt[b], 1);
        if (pos < BCAP)
            arena[(size_t)b * BCAP + pos] = ((unsigned)src << WIN_BITS) | (unsigned)(dst & (WIN - 1));
    }
}

// ---------------------------------------------------------------------------
// Scan bucket totals -> exclusive bucket offsets. 1 block.
// ---------------------------------------------------------------------------
__global__ void scan_buckets(const int* __restrict__ gcur, int* __restrict__ bukoff,
                             int* __restrict__ offsets, int n, int total) {
    __shared__ int s[128];
    int t = threadIdx.x;
    int v = (t < NBUK) ? gcur[t] : 0;
    s[t] = v;
    __syncthreads();
    for (int off = 1; off < 128; off <<= 1) {
        int u = (t >= off) ? s[t - off] : 0;
        __syncthreads();
        s[t] += u;
        __syncthreads();
    }
    if (t < NBUK) bukoff[t] = s[t] - v;
    if (t == 0) offsets[n] = total;
}

// ---------------------------------------------------------------------------
// P1: per-bucket histogram + intra-bucket scan -> offsets, dinv.
// ---------------------------------------------------------------------------
__global__ __launch_bounds__(256) void p1_count_scan(const unsigned* __restrict__ arena,
                                                     const int* __restrict__ gcur,
                                                     const int* __restrict__ bukoff,
                                                     int* __restrict__ offsets,
                                                     float* __restrict__ dinv, int n) {
    __shared__ int cnt[WIN];
    __shared__ int sbuf[256];
    int b = blockIdx.x, tid = threadIdx.x;
    cnt[tid] = 0; cnt[tid + 256] = 0;
    __syncthreads();
    int m = gcur[b]; if (m > BCAP) m = BCAP;
    const unsigned* a = arena + (size_t)b * BCAP;
    for (int i = tid; i < m; i += 256) atomicAdd(&cnt[a[i] & (WIN - 1)], 1);
    __syncthreads();
    int j0 = tid * 2;
    int a0 = cnt[j0], a1 = cnt[j0 + 1];
    int ts = a0 + a1;
    sbuf[tid] = ts;
    __syncthreads();
    for (int off = 1; off < 256; off <<= 1) {
        int u = (tid >= off) ? sbuf[tid - off] : 0;
        __syncthreads();
        sbuf[tid] += u;
        __syncthreads();
    }
    int pre = sbuf[tid] - ts;
    int base = b << WIN_BITS;
    int o0 = bukoff[b] + pre, o1 = o0 + a0;
    int d0 = base + j0;
    if (d0 + 1 < n) {
        *(int2*)&offsets[d0] = make_int2(o0, o1);
        *(float2*)&dinv[d0] = make_float2(rsqrtf((float)(a0 + 1)), rsqrtf((float)(a1 + 1)));
    } else if (d0 < n) {
        offsets[d0] = o0;
        dinv[d0] = rsqrtf((float)(a0 + 1));
    }
}

// ---------------------------------------------------------------------------
// P2: per-bucket CSR fill.
// ---------------------------------------------------------------------------
__global__ __launch_bounds__(256) void p2_fill(const unsigned* __restrict__ arena,
                                               const int* __restrict__ gcur,
                                               const int* __restrict__ offsets,
                                               int* __restrict__ csr_src, int n) {
    __shared__ int cur[WIN];
    int b = blockIdx.x, tid = threadIdx.x;
    int base = b << WIN_BITS;
    for (int j = tid; j < WIN; j += 256) {
        int d = base + j;
        cur[j] = (d < n) ? offsets[d] : 0;
    }
    __syncthreads();
    int m = gcur[b]; if (m > BCAP) m = BCAP;
    const unsigned* a = arena + (size_t)b * BCAP;
    for (int i = tid; i < m; i += 256) {
        unsigned e = a[i];
        int pos = atomicAdd(&cur[e & (WIN - 1)], 1);
        csr_src[pos] = (int)(e >> WIN_BITS);
    }
}

// ---------------------------------------------------------------------------
// All W fp32 -> fp16 fragment-order conversions in ONE dispatch.
// Wfrag[(sq*FO + col)*8 + j] = W[(sq*8 + j)*FO + col],  sq in [0,16).
// blocks 0-7: W1(128), 8-15: W2(128), 16-23: W3(128), 24-27: W4(64).
// ---------------------------------------------------------------------------
__global__ __launch_bounds__(256) void wfrag_all(
        const float* __restrict__ W1, const float* __restrict__ W2,
        const float* __restrict__ W3, const float* __restrict__ W4,
        _Float16* __restrict__ Wf1, _Float16* __restrict__ Wf2,
        _Float16* __restrict__ Wf3, _Float16* __restrict__ Wf4) {
    int b = blockIdx.x;
    const float* W; _Float16* Wf; int FO; int lb;
    if (b < 8)       { W = W1; Wf = Wf1; FO = 128; lb = b; }
    else if (b < 16) { W = W2; Wf = Wf2; FO = 128; lb = b - 8; }
    else if (b < 24) { W = W3; Wf = Wf3; FO = 128; lb = b - 16; }
    else             { W = W4; Wf = Wf4; FO = 64;  lb = b - 24; }
    int g = lb * 256 + threadIdx.x;
    if (g >= 16 * FO) return;
    int col = g % FO;
    int sq = g / FO;
    int k0 = sq * 8;
    half8 hv;
    #pragma unroll
    for (int j = 0; j < 8; ++j)
        hv[j] = (_Float16)W[(size_t)(k0 + j) * FO + col];
    *(half8*)&Wf[(size_t)g * 8] = hv;
}

// ---------------------------------------------------------------------------
// MFMA GEMM (layer 1), LDS-free: W-fragments from global (L1-broadcast).
// h[i][j] = fp16( (x[i,:] @ W[:,j]) * dinv[i] ), FI=128.
// ---------------------------------------------------------------------------
__global__ __launch_bounds__(256) void gemm_mfma_kernel(
        const float* __restrict__ x, const _Float16* __restrict__ Wfrag,
        const float* __restrict__ dinv, __half* __restrict__ h, int n) {
    constexpr int FO = 128;
    constexpr int NT = FO / 16;
    int tid = threadIdx.x;
    int ln = tid & 15;
    int q  = (tid >> 4) & 3;
    int w  = tid >> 6;
    int node = blockIdx.x * 64 + w * 16 + ln;
    int nodec = node < n ? node : n - 1;
    const float* xrow = x + (size_t)nodec * 128;

    floatx4 acc[NT];
    #pragma unroll
    for (int t = 0; t < NT; ++t) acc[t] = (floatx4){0.f, 0.f, 0.f, 0.f};

    #pragma unroll
    for (int s = 0; s < 4; ++s) {
        const float* xp = xrow + s * 32 + q * 8;
        float4 a0 = *(const float4*)xp;
        float4 a1 = *(const float4*)(xp + 4);
        half8 xf;
        xf[0] = (_Float16)a0.x; xf[1] = (_Float16)a0.y;
        xf[2] = (_Float16)a0.z; xf[3] = (_Float16)a0.w;
        xf[4] = (_Float16)a1.x; xf[5] = (_Float16)a1.y;
        xf[6] = (_Float16)a1.z; xf[7] = (_Float16)a1.w;
        int sq = s * 4 + q;
        #pragma unroll
        for (int t = 0; t < NT; ++t) {
            half8 wf = *(const half8*)&Wfrag[(size_t)(sq * FO + t * 16 + ln) * 8];
            acc[t] = __builtin_amdgcn_mfma_f32_16x16x32_f16(wf, xf, acc[t], 0, 0, 0);
        }
    }

    if (node < n) {
        float dv = dinv[node];
        __half* hrow = h + (size_t)node * FO;
        #pragma unroll
        for (int t = 0; t < NT; ++t) {
            __half2 p[2];
            p[0] = __float22half2_rn(make_float2(acc[t][0] * dv, acc[t][1] * dv));
            p[1] = __float22half2_rn(make_float2(acc[t][2] * dv, acc[t][3] * dv));
            *(uint2*)&hrow[t * 16 + q * 4] = *(const uint2*)p;
        }
    }
}

// ---------------------------------------------------------------------------
// Fused agg_i + gemm_{i+1}: block = 64 nodes, 512 threads (8 waves).
// Phase A (wide gather): quarter-wave qw (16 lanes x 16B dwordx4) gathers one
// 256-B row -> ONE instruction covers 4 edges; x2 unroll = 8 edges in flight.
// Lane sl holds feats sl*8..sl*8+8 in fp32; xor-16/32 reduce at node end.
// Phase B: MFMA with global W-fragments (no W in LDS; LDS = 17.4 KB).
// ---------------------------------------------------------------------------
template<int FO>
__global__ __launch_bounds__(512) void fused_agg_gemm(
        const _Float16* __restrict__ hin, const int* __restrict__ offsets,
        const int* __restrict__ csr_src, const float* __restrict__ dinv,
        const float* __restrict__ bias, const _Float16* __restrict__ Wfrag,
        __half* __restrict__ hout, int n) {
    constexpr int NT  = FO / 16;
    constexpr int TPW = NT / 2;                  // tiles per wave (cg in {0,1})
    __shared__ _Float16 aggL[64 * 136];          // 17.4 KB, padded stride

    int tid = threadIdx.x;
    int w = tid >> 6;
    int lane = tid & 63;
    int qw = lane >> 4, sl = lane & 15;
    float4 bb0 = *(const float4*)&bias[sl * 8];
    float4 bb1 = *(const float4*)&bias[sl * 8 + 4];

    for (int ii = 0; ii < 8; ++ii) {
        int c = blockIdx.x * 64 + w * 8 + ii;
        if (c >= n) break;
        c = __builtin_amdgcn_readfirstlane(c);
        float acc[8] = {0.f, 0.f, 0.f, 0.f, 0.f, 0.f, 0.f, 0.f};
        if (qw == 0)
            acc8(acc, *(const half8*)&hin[(size_t)c * 128 + sl * 8]);   // self loop
        int s = offsets[c], e = offsets[c + 1];
        int i = s;
        for (; i + 7 < e; i += 8) {
            int sa = csr_src[i + qw];
            int sb = csr_src[i + 4 + qw];
            half8 va = *(const half8*)&hin[(size_t)sa * 128 + sl * 8];
            half8 vb = *(const half8*)&hin[(size_t)sb * 128 + sl * 8];
            acc8(acc, va);
            acc8(acc, vb);
        }
        for (; i + 3 < e; i += 4) {
            int sa = csr_src[i + qw];
            acc8(acc, *(const half8*)&hin[(size_t)sa * 128 + sl * 8]);
        }
        if (i + qw < e) {
            int sa = csr_src[i + qw];
            acc8(acc, *(const half8*)&hin[(size_t)sa * 128 + sl * 8]);
        }
        #pragma unroll
        for (int k = 0; k < 8; ++k) {
            acc[k] += __shfl_xor(acc[k], 16);
            acc[k] += __shfl_xor(acc[k], 32);
        }
        if (qw == 0) {
            float dc = dinv[c];
            float v0 = fmaxf(fmaf(acc[0], dc, bb0.x), 0.f);
            float v1 = fmaxf(fmaf(acc[1], dc, bb0.y), 0.f);
            float v2 = fmaxf(fmaf(acc[2], dc, bb0.z), 0.f);
            float v3 = fmaxf(fmaf(acc[3], dc, bb0.w), 0.f);
            float v4 = fmaxf(fmaf(acc[4], dc, bb1.x), 0.f);
            float v5 = fmaxf(fmaf(acc[5], dc, bb1.y), 0.f);
            float v6 = fmaxf(fmaf(acc[6], dc, bb1.z), 0.f);
            float v7 = fmaxf(fmaf(acc[7], dc, bb1.w), 0.f);
            half8 hv;
            hv[0] = (_Float16)v0; hv[1] = (_Float16)v1;
            hv[2] = (_Float16)v2; hv[3] = (_Float16)v3;
            hv[4] = (_Float16)v4; hv[5] = (_Float16)v5;
            hv[6] = (_Float16)v6; hv[7] = (_Float16)v7;
            *(half8*)&aggL[(size_t)(w * 8 + ii) * 136 + sl * 8] = hv;
        }
    }
    __syncthreads();

    // ---- phase B: MFMA. wave = (nodegroup ng 0..3, colgroup cg 0..1) ----
    int ng = w & 3, cg = w >> 2;
    int ln = tid & 15;
    int q  = (tid >> 4) & 3;
    int nl = ng * 16 + ln;                       // node local 0..63
    int node = blockIdx.x * 64 + nl;

    floatx4 acc[TPW];
    #pragma unroll
    for (int t = 0; t < TPW; ++t) acc[t] = (floatx4){0.f, 0.f, 0.f, 0.f};

    #pragma unroll
    for (int s = 0; s < 4; ++s) {
        half8 xf = *(const half8*)&aggL[(size_t)nl * 136 + s * 32 + q * 8];
        int sq = s * 4 + q;
        #pragma unroll
        for (int t = 0; t < TPW; ++t) {
            int T = cg * TPW + t;
            half8 wf = *(const half8*)&Wfrag[(size_t)(sq * FO + T * 16 + ln) * 8];
            acc[t] = __builtin_amdgcn_mfma_f32_16x16x32_f16(wf, xf, acc[t], 0, 0, 0);
        }
    }

    if (node < n) {
        float dv = dinv[node];
        __half* hrow = hout + (size_t)node * FO;
        #pragma unroll
        for (int t = 0; t < TPW; ++t) {
            int T = cg * TPW + t;
            __half2 p[2];
            p[0] = __float22half2_rn(make_float2(acc[t][0] * dv, acc[t][1] * dv));
            p[1] = __float22half2_rn(make_float2(acc[t][2] * dv, acc[t][3] * dv));
            *(uint2*)&hrow[T * 16 + q * 4] = *(const uint2*)p;
        }
    }
}

// ---------------------------------------------------------------------------
// Final aggregation (FO=64): eighth-wave (8 lanes x 16 B) gathers one 128-B
// row -> one instruction covers 8 edges; xor-8/16/32 reduce; fp32 out.
// ---------------------------------------------------------------------------
__global__ __launch_bounds__(256) void agg64_kernel(
        const _Float16* __restrict__ h, const int* __restrict__ offsets,
        const int* __restrict__ csr_src, const float* __restrict__ dinv,
        const float* __restrict__ bias, float* __restrict__ out, int n) {
    int lane = threadIdx.x & 63;
    int o = lane >> 3, sl = lane & 7;
    int c = (blockIdx.x << 2) + (threadIdx.x >> 6);
    if (c >= n) return;
    c = __builtin_amdgcn_readfirstlane(c);
    float acc[8] = {0.f, 0.f, 0.f, 0.f, 0.f, 0.f, 0.f, 0.f};
    if (o == 0)
        acc8(acc, *(const half8*)&h[(size_t)c * 64 + sl * 8]);   // self loop
    int s = offsets[c], e = offsets[c + 1];
    int i = s;
    for (; i + 15 < e; i += 16) {
        int sa = csr_src[i + o];
        int sb = csr_src[i + 8 + o];
        half8 va = *(const half8*)&h[(size_t)sa * 64 + sl * 8];
        half8 vb = *(const half8*)&h[(size_t)sb * 64 + sl * 8];
        acc8(acc, va);
        acc8(acc, vb);
    }
    for (; i + 7 < e; i += 8) {
        int sa = csr_src[i + o];
        acc8(acc, *(const half8*)&h[(size_t)sa * 64 + sl * 8]);
    }
    if (i + o < e) {
        int sa = csr_src[i + o];
        acc8(acc, *(const half8*)&h[(size_t)sa * 64 + sl * 8]);
    }
    #pragma unroll
    for (int k = 0; k < 8; ++k) {
        acc[k] += __shfl_xor(acc[k], 8);
        acc[k] += __shfl_xor(acc[k], 16);
        acc[k] += __shfl_xor(acc[k], 32);
    }
    if (o == 0) {
        float dc = dinv[c];
        float4 bb0 = *(const float4*)&bias[sl * 8];
        float4 bb1 = *(const float4*)&bias[sl * 8 + 4];
        float4 o0, o1;
        o0.x = fmaf(acc[0], dc, bb0.x); o0.y = fmaf(acc[1], dc, bb0.y);
        o0.z = fmaf(acc[2], dc, bb0.z); o0.w = fmaf(acc[3], dc, bb0.w);
        o1.x = fmaf(acc[4], dc, bb1.x); o1.y = fmaf(acc[5], dc, bb1.y);
        o1.z = fmaf(acc[6], dc, bb1.z); o1.w = fmaf(acc[7], dc, bb1.w);
        float* orow = out + (size_t)c * 64 + sl * 8;
        *(float4*)orow = o0;
        *(float4*)(orow + 4) = o1;
    }
}

// ---------------------------------------------------------------------------

extern "C" void kernel_launch(void* const* d_in, const int* in_sizes, int n_in,
                              void* d_out, int out_size, void* d_ws, size_t ws_size,
                              hipStream_t stream) {
    const float* x  = (const float*)d_in[0];
    const int*   ei = (const int*)  d_in[1];
    const float* W1 = (const float*)d_in[2];
    const float* b1 = (const float*)d_in[3];
    const float* W2 = (const float*)d_in[4];
    const float* b2 = (const float*)d_in[5];
    const float* W3 = (const float*)d_in[6];
    const float* b3 = (const float*)d_in[7];
    const float* W4 = (const float*)d_in[8];
    const float* b4 = (const float*)d_in[9];

    const int N = N_NODES, E = N_EDGES;

    char* p = (char*)d_ws;
    auto carve = [&](size_t bytes) {
        char* q = p;
        p += (bytes + 255) & ~(size_t)255;
        return (void*)q;
    };
    int*       offsets = (int*)      carve((size_t)(N + 1) * 4);
    int*       csr_src = (int*)      carve((size_t)E * 4);
    float*     dinv    = (float*)    carve((size_t)N * 4);
    int*       gcur    = (int*)      carve((size_t)NBUK * 4);
    int*       bukoff  = (int*)      carve((size_t)NBUK * 4);
    unsigned*  arena   = (unsigned*) carve((size_t)NBUK * BCAP * 4);
    _Float16*  Wf1     = (_Float16*) carve((size_t)16 * 128 * 8 * 2);   // 32 KB
    _Float16*  Wf2     = (_Float16*) carve((size_t)16 * 128 * 8 * 2);
    _Float16*  Wf3     = (_Float16*) carve((size_t)16 * 128 * 8 * 2);
    _Float16*  Wf4     = (_Float16*) carve((size_t)16 * 64 * 8 * 2);    // 16 KB
    __half*    A1      = (__half*)   carve((size_t)N * 128 * 2);
    __half*    A2      = (__half*)   carve((size_t)N * 128 * 2);

    // ---- graph build + W conversion (6 dispatches) ----
    hipMemsetAsync(gcur, 0, (size_t)NBUK * 4, stream);
    p0_bucket<<<512, 256, 0, stream>>>(ei, gcur, arena, E);
    scan_buckets<<<1, 128, 0, stream>>>(gcur, bukoff, offsets, N, E);
    p1_count_scan<<<NBUK, 256, 0, stream>>>(arena, gcur, bukoff, offsets, dinv, N);
    p2_fill<<<NBUK, 256, 0, stream>>>(arena, gcur, offsets, csr_src, N);
    wfrag_all<<<28, 256, 0, stream>>>(W1, W2, W3, W4, Wf1, Wf2, Wf3, Wf4);

    // ---- layers (5 dispatches) ----
    const int nb64 = (N + 63) / 64;    // 782

    gemm_mfma_kernel<<<nb64, 256, 0, stream>>>(x, Wf1, dinv, A1, N);
    fused_agg_gemm<128><<<nb64, 512, 0, stream>>>((const _Float16*)A1, offsets, csr_src, dinv, b1, Wf2, A2, N);
    fused_agg_gemm<128><<<nb64, 512, 0, stream>>>((const _Float16*)A2, offsets, csr_src, dinv, b2, Wf3, A1, N);
    fused_agg_gemm<64><<<nb64, 512, 0, stream>>>((const _Float16*)A1, offsets, csr_src, dinv, b3, Wf4, A2, N);
    agg64_kernel<<<(N + 3) / 4, 256, 0, stream>>>((const _Float16*)A2, offsets, csr_src, dinv, b4, (float*)d_out, N);
}

// Round 14
// 277.033 us; speedup vs baseline: 1.1348x; 1.0136x over previous
//
#include <hip/hip_runtime.h>
#include <hip/hip_fp16.h>
#include <type_traits>

#define N_NODES 50000
#define N_EDGES 800000
#define WIN_BITS 9
#define WIN 512
#define NBUK ((N_NODES + WIN - 1) / WIN)   // 98
#define BCAP 16384

typedef _Float16 half8 __attribute__((ext_vector_type(8)));
typedef float floatx4 __attribute__((ext_vector_type(4)));

__device__ inline void acc8(float* a, half8 v) {
    const __half2* p = (const __half2*)&v;
    float2 f0 = __half22float2(p[0]);
    float2 f1 = __half22float2(p[1]);
    float2 f2 = __half22float2(p[2]);
    float2 f3 = __half22float2(p[3]);
    a[0] += f0.x; a[1] += f0.y; a[2] += f1.x; a[3] += f1.y;
    a[4] += f2.x; a[5] += f2.y; a[6] += f3.x; a[7] += f3.y;
}

// ---------------------------------------------------------------------------
// P0 + wfrag combined. Blocks [0,512): bucket edges by dest window.
// Blocks [512,540): W fp32 -> fp16 fragment-order conversion.
// ---------------------------------------------------------------------------
__global__ __launch_bounds__(256) void p0_wfrag(
        const int* __restrict__ ei, int* __restrict__ gcur,
        unsigned* __restrict__ arena, int E,
        const float* __restrict__ W1, const float* __restrict__ W2,
        const float* __restrict__ W3, const float* __restrict__ W4,
        _Float16* __restrict__ Wf1, _Float16* __restrict__ Wf2,
        _Float16* __restrict__ Wf3, _Float16* __restrict__ Wf4) {
    int tid = threadIdx.x;
    if (blockIdx.x >= 512) {
        int b = blockIdx.x - 512;
        const float* W; _Float16* Wf; int FO; int lb;
        if (b < 8)       { W = W1; Wf = Wf1; FO = 128; lb = b; }
        else if (b < 16) { W = W2; Wf = Wf2; FO = 128; lb = b - 8; }
        else if (b < 24) { W = W3; Wf = Wf3; FO = 128; lb = b - 16; }
        else             { W = W4; Wf = Wf4; FO = 64;  lb = b - 24; }
        int g = lb * 256 + tid;
        if (g >= 16 * FO) return;
        int col = g % FO;
        int sq = g / FO;
        int k0 = sq * 8;
        half8 hv;
        #pragma unroll
        for (int j = 0; j < 8; ++j)
            hv[j] = (_Float16)W[(size_t)(k0 + j) * FO + col];
        *(half8*)&Wf[(size_t)g * 8] = hv;
        return;
    }
    __shared__ int lcnt[NBUK];
    __shared__ int lbase[NBUK];
    int chunk = (E + 511) / 512;
    int e0 = blockIdx.x * chunk;
    int e1 = e0 + chunk; if (e1 > E) e1 = E;
    for (int b = tid; b < NBUK; b += 256) lcnt[b] = 0;
    __syncthreads();
    for (int e = e0 + tid; e < e1; e += 256) {
        int dst = ei[E + e];
        atomicAdd(&lcnt[dst >> WIN_BITS], 1);
    }
    __syncthreads();
    for (int b = tid; b < NBUK; b += 256) {
        lbase[b] = atomicAdd(&gcur[b], lcnt[b]);
        lcnt[b] = 0;
    }
    __syncthreads();
    for (int e = e0 + tid; e < e1; e += 256) {
        int dst = ei[E + e];
        int src = ei[e];
        int b = dst >> WIN_BITS;
        int pos = lbase[b] + atomicAdd(&lcnt[b], 1);
        if (pos < BCAP)
            arena[(size_t)b * BCAP + pos] = ((unsigned)src << WIN_BITS) | (unsigned)(dst & (WIN - 1));
    }
}

// ---------------------------------------------------------------------------
// build_graph: per-bucket, one pass. Local prefix over gcur (98 entries) ->
// bucket offset; LDS histogram; intra-bucket scan -> offsets/dinv; CSR fill.
// ---------------------------------------------------------------------------
__global__ __launch_bounds__(256) void build_graph(
        const unsigned* __restrict__ arena, const int* __restrict__ gcur,
        int* __restrict__ offsets, float* __restrict__ dinv,
        int* __restrict__ csr_src, int n, int total) {
    __shared__ int cnt[WIN];
    __shared__ int sbuf[256];
    __shared__ int bukoff_s;
    int b = blockIdx.x, tid = threadIdx.x;

    sbuf[tid] = (tid < b) ? gcur[tid] : 0;       // b <= 97 < 256
    cnt[tid] = 0; cnt[tid + 256] = 0;
    __syncthreads();
    #pragma unroll
    for (int off = 128; off > 0; off >>= 1) {
        if (tid < off) sbuf[tid] += sbuf[tid + off];
        __syncthreads();
    }
    if (tid == 0) bukoff_s = sbuf[0];

    int m = gcur[b]; if (m > BCAP) m = BCAP;
    const unsigned* a = arena + (size_t)b * BCAP;
    for (int i = tid; i < m; i += 256) atomicAdd(&cnt[a[i] & (WIN - 1)], 1);
    __syncthreads();

    int j0 = tid * 2;
    int a0 = cnt[j0], a1 = cnt[j0 + 1];
    int ts = a0 + a1;
    sbuf[tid] = ts;
    __syncthreads();
    for (int off = 1; off < 256; off <<= 1) {
        int u = (tid >= off) ? sbuf[tid - off] : 0;
        __syncthreads();
        sbuf[tid] += u;
        __syncthreads();
    }
    int pre = sbuf[tid] - ts;
    int base = b << WIN_BITS;
    int o0 = bukoff_s + pre, o1 = o0 + a0;
    int d0 = base + j0;
    if (d0 + 1 < n) {
        *(int2*)&offsets[d0] = make_int2(o0, o1);
        *(float2*)&dinv[d0] = make_float2(rsqrtf((float)(a0 + 1)), rsqrtf((float)(a1 + 1)));
    } else if (d0 < n) {
        offsets[d0] = o0;
        dinv[d0] = rsqrtf((float)(a0 + 1));
    }
    __syncthreads();
    cnt[j0] = o0; cnt[j0 + 1] = o1;              // reuse as cursors
    __syncthreads();
    for (int i = tid; i < m; i += 256) {
        unsigned e = a[i];
        int pos = atomicAdd(&cnt[e & (WIN - 1)], 1);
        csr_src[pos] = (int)(e >> WIN_BITS);
    }
    if (b == 0 && tid == 0) offsets[n] = total;
}

// ---------------------------------------------------------------------------
// MFMA GEMM (layer 1), LDS-free: W-fragments from global (L1-broadcast).
// ---------------------------------------------------------------------------
__global__ __launch_bounds__(256) void gemm_mfma_kernel(
        const float* __restrict__ x, const _Float16* __restrict__ Wfrag,
        const float* __restrict__ dinv, __half* __restrict__ h, int n) {
    constexpr int FO = 128;
    constexpr int NT = FO / 16;
    int tid = threadIdx.x;
    int ln = tid & 15;
    int q  = (tid >> 4) & 3;
    int w  = tid >> 6;
    int node = blockIdx.x * 64 + w * 16 + ln;
    int nodec = node < n ? node : n - 1;
    const float* xrow = x + (size_t)nodec * 128;

    floatx4 acc[NT];
    #pragma unroll
    for (int t = 0; t < NT; ++t) acc[t] = (floatx4){0.f, 0.f, 0.f, 0.f};

    #pragma unroll
    for (int s = 0; s < 4; ++s) {
        const float* xp = xrow + s * 32 + q * 8;
        float4 a0 = *(const float4*)xp;
        float4 a1 = *(const float4*)(xp + 4);
        half8 xf;
        xf[0] = (_Float16)a0.x; xf[1] = (_Float16)a0.y;
        xf[2] = (_Float16)a0.z; xf[3] = (_Float16)a0.w;
        xf[4] = (_Float16)a1.x; xf[5] = (_Float16)a1.y;
        xf[6] = (_Float16)a1.z; xf[7] = (_Float16)a1.w;
        int sq = s * 4 + q;
        #pragma unroll
        for (int t = 0; t < NT; ++t) {
            half8 wf = *(const half8*)&Wfrag[(size_t)(sq * FO + t * 16 + ln) * 8];
            acc[t] = __builtin_amdgcn_mfma_f32_16x16x32_f16(wf, xf, acc[t], 0, 0, 0);
        }
    }

    if (node < n) {
        float dv = dinv[node];
        __half* hrow = h + (size_t)node * FO;
        #pragma unroll
        for (int t = 0; t < NT; ++t) {
            __half2 p[2];
            p[0] = __float22half2_rn(make_float2(acc[t][0] * dv, acc[t][1] * dv));
            p[1] = __float22half2_rn(make_float2(acc[t][2] * dv, acc[t][3] * dv));
            *(uint2*)&hrow[t * 16 + q * 4] = *(const uint2*)p;
        }
    }
}

// ---------------------------------------------------------------------------
// Fused agg_i + gemm_{i+1}: block = 64 nodes, 512 threads (8 waves).
// Phase A: TWO-NODE INTERLEAVED wide gather. Each wave processes node pairs
// with two independent edge cursors -> 2 independent index-load + gather
// chains in flight (2x MLP vs single-cursor). Quarter-wave (16 lanes x 16 B)
// gathers one 256-B row per instruction.
// Phase B: MFMA with global W-fragments (no W in LDS; LDS = 17.4 KB).
// ---------------------------------------------------------------------------
template<int FO>
__global__ __launch_bounds__(512) void fused_agg_gemm(
        const _Float16* __restrict__ hin, const int* __restrict__ offsets,
        const int* __restrict__ csr_src, const float* __restrict__ dinv,
        const float* __restrict__ bias, const _Float16* __restrict__ Wfrag,
        __half* __restrict__ hout, int n) {
    constexpr int NT  = FO / 16;
    constexpr int TPW = NT / 2;                  // tiles per wave (cg in {0,1})
    __shared__ _Float16 aggL[64 * 136];          // 17.4 KB, padded stride

    int tid = threadIdx.x;
    int w = tid >> 6;
    int lane = tid & 63;
    int qw = lane >> 4, sl = lane & 15;
    float4 bb0 = *(const float4*)&bias[sl * 8];
    float4 bb1 = *(const float4*)&bias[sl * 8 + 4];

    for (int pp = 0; pp < 4; ++pp) {
        int c0 = blockIdx.x * 64 + w * 8 + pp * 2;
        if (c0 >= n) break;                      // wave-uniform
        int c1 = c0 + 1;
        bool v1 = c1 < n;
        c0 = __builtin_amdgcn_readfirstlane(c0);
        c1 = __builtin_amdgcn_readfirstlane(c1);

        float a0[8] = {0.f, 0.f, 0.f, 0.f, 0.f, 0.f, 0.f, 0.f};
        float a1[8] = {0.f, 0.f, 0.f, 0.f, 0.f, 0.f, 0.f, 0.f};
        if (qw == 0) acc8(a0, *(const half8*)&hin[(size_t)c0 * 128 + sl * 8]);
        if (v1 && qw == 0) acc8(a1, *(const half8*)&hin[(size_t)c1 * 128 + sl * 8]);

        int i0 = offsets[c0], e0 = offsets[c0 + 1];
        int i1 = v1 ? offsets[c1] : 0, e1 = v1 ? offsets[c1 + 1] : 0;

        // interleaved main loop: 4+4 edges per iteration, 2 independent chains
        while (i0 + 3 < e0 && i1 + 3 < e1) {
            int sa = csr_src[i0 + qw];
            int sb = csr_src[i1 + qw];
            half8 va = *(const half8*)&hin[(size_t)sa * 128 + sl * 8];
            half8 vb = *(const half8*)&hin[(size_t)sb * 128 + sl * 8];
            acc8(a0, va);
            acc8(a1, vb);
            i0 += 4; i1 += 4;
        }
        for (; i0 + 3 < e0; i0 += 4) {
            int sa = csr_src[i0 + qw];
            acc8(a0, *(const half8*)&hin[(size_t)sa * 128 + sl * 8]);
        }
        if (i0 + qw < e0) {
            int sa = csr_src[i0 + qw];
            acc8(a0, *(const half8*)&hin[(size_t)sa * 128 + sl * 8]);
        }
        for (; i1 + 3 < e1; i1 += 4) {
            int sb = csr_src[i1 + qw];
            acc8(a1, *(const half8*)&hin[(size_t)sb * 128 + sl * 8]);
        }
        if (v1 && i1 + qw < e1) {
            int sb = csr_src[i1 + qw];
            acc8(a1, *(const half8*)&hin[(size_t)sb * 128 + sl * 8]);
        }

        #pragma unroll
        for (int k = 0; k < 8; ++k) {
            a0[k] += __shfl_xor(a0[k], 16);
            a0[k] += __shfl_xor(a0[k], 32);
            a1[k] += __shfl_xor(a1[k], 16);
            a1[k] += __shfl_xor(a1[k], 32);
        }
        if (qw == 0) {
            {
                float dc = dinv[c0];
                half8 hv;
                hv[0] = (_Float16)fmaxf(fmaf(a0[0], dc, bb0.x), 0.f);
                hv[1] = (_Float16)fmaxf(fmaf(a0[1], dc, bb0.y), 0.f);
                hv[2] = (_Float16)fmaxf(fmaf(a0[2], dc, bb0.z), 0.f);
                hv[3] = (_Float16)fmaxf(fmaf(a0[3], dc, bb0.w), 0.f);
                hv[4] = (_Float16)fmaxf(fmaf(a0[4], dc, bb1.x), 0.f);
                hv[5] = (_Float16)fmaxf(fmaf(a0[5], dc, bb1.y), 0.f);
                hv[6] = (_Float16)fmaxf(fmaf(a0[6], dc, bb1.z), 0.f);
                hv[7] = (_Float16)fmaxf(fmaf(a0[7], dc, bb1.w), 0.f);
                *(half8*)&aggL[(size_t)(w * 8 + pp * 2) * 136 + sl * 8] = hv;
            }
            if (v1) {
                float dc = dinv[c1];
                half8 hv;
                hv[0] = (_Float16)fmaxf(fmaf(a1[0], dc, bb0.x), 0.f);
                hv[1] = (_Float16)fmaxf(fmaf(a1[1], dc, bb0.y), 0.f);
                hv[2] = (_Float16)fmaxf(fmaf(a1[2], dc, bb0.z), 0.f);
                hv[3] = (_Float16)fmaxf(fmaf(a1[3], dc, bb0.w), 0.f);
                hv[4] = (_Float16)fmaxf(fmaf(a1[4], dc, bb1.x), 0.f);
                hv[5] = (_Float16)fmaxf(fmaf(a1[5], dc, bb1.y), 0.f);
                hv[6] = (_Float16)fmaxf(fmaf(a1[6], dc, bb1.z), 0.f);
                hv[7] = (_Float16)fmaxf(fmaf(a1[7], dc, bb1.w), 0.f);
                *(half8*)&aggL[(size_t)(w * 8 + pp * 2 + 1) * 136 + sl * 8] = hv;
            }
        }
    }
    __syncthreads();

    // ---- phase B: MFMA. wave = (nodegroup ng 0..3, colgroup cg 0..1) ----
    int ng = w & 3, cg = w >> 2;
    int ln = tid & 15;
    int q  = (tid >> 4) & 3;
    int nl = ng * 16 + ln;                       // node local 0..63
    int node = blockIdx.x * 64 + nl;

    floatx4 acc[TPW];
    #pragma unroll
    for (int t = 0; t < TPW; ++t) acc[t] = (floatx4){0.f, 0.f, 0.f, 0.f};

    #pragma unroll
    for (int s = 0; s < 4; ++s) {
        half8 xf = *(const half8*)&aggL[(size_t)nl * 136 + s * 32 + q * 8];
        int sq = s * 4 + q;
        #pragma unroll
        for (int t = 0; t < TPW; ++t) {
            int T = cg * TPW + t;
            half8 wf = *(const half8*)&Wfrag[(size_t)(sq * FO + T * 16 + ln) * 8];
            acc[t] = __builtin_amdgcn_mfma_f32_16x16x32_f16(wf, xf, acc[t], 0, 0, 0);
        }
    }

    if (node < n) {
        float dv = dinv[node];
        __half* hrow = hout + (size_t)node * FO;
        #pragma unroll
        for (int t = 0; t < TPW; ++t) {
            int T = cg * TPW + t;
            __half2 p[2];
            p[0] = __float22half2_rn(make_float2(acc[t][0] * dv, acc[t][1] * dv));
            p[1] = __float22half2_rn(make_float2(acc[t][2] * dv, acc[t][3] * dv));
            *(uint2*)&hrow[T * 16 + q * 4] = *(const uint2*)p;
        }
    }
}

// ---------------------------------------------------------------------------
// Final aggregation (FO=64): eighth-wave (8 lanes x 16 B) gathers one 128-B
// row -> one instruction covers 8 edges; xor-8/16/32 reduce; fp32 out.
// ---------------------------------------------------------------------------
__global__ __launch_bounds__(256) void agg64_kernel(
        const _Float16* __restrict__ h, const int* __restrict__ offsets,
        const int* __restrict__ csr_src, const float* __restrict__ dinv,
        const float* __restrict__ bias, float* __restrict__ out, int n) {
    int lane = threadIdx.x & 63;
    int o = lane >> 3, sl = lane & 7;
    int c = (blockIdx.x << 2) + (threadIdx.x >> 6);
    if (c >= n) return;
    c = __builtin_amdgcn_readfirstlane(c);
    float acc[8] = {0.f, 0.f, 0.f, 0.f, 0.f, 0.f, 0.f, 0.f};
    if (o == 0)
        acc8(acc, *(const half8*)&h[(size_t)c * 64 + sl * 8]);   // self loop
    int s = offsets[c], e = offsets[c + 1];
    int i = s;
    for (; i + 15 < e; i += 16) {
        int sa = csr_src[i + o];
        int sb = csr_src[i + 8 + o];
        half8 va = *(const half8*)&h[(size_t)sa * 64 + sl * 8];
        half8 vb = *(const half8*)&h[(size_t)sb * 64 + sl * 8];
        acc8(acc, va);
        acc8(acc, vb);
    }
    for (; i + 7 < e; i += 8) {
        int sa = csr_src[i + o];
        acc8(acc, *(const half8*)&h[(size_t)sa * 64 + sl * 8]);
    }
    if (i + o < e) {
        int sa = csr_src[i + o];
        acc8(acc, *(const half8*)&h[(size_t)sa * 64 + sl * 8]);
    }
    #pragma unroll
    for (int k = 0; k < 8; ++k) {
        acc[k] += __shfl_xor(acc[k], 8);
        acc[k] += __shfl_xor(acc[k], 16);
        acc[k] += __shfl_xor(acc[k], 32);
    }
    if (o == 0) {
        float dc = dinv[c];
        float4 bb0 = *(const float4*)&bias[sl * 8];
        float4 bb1 = *(const float4*)&bias[sl * 8 + 4];
        float4 o0, o1;
        o0.x = fmaf(acc[0], dc, bb0.x); o0.y = fmaf(acc[1], dc, bb0.y);
        o0.z = fmaf(acc[2], dc, bb0.z); o0.w = fmaf(acc[3], dc, bb0.w);
        o1.x = fmaf(acc[4], dc, bb1.x); o1.y = fmaf(acc[5], dc, bb1.y);
        o1.z = fmaf(acc[6], dc, bb1.z); o1.w = fmaf(acc[7], dc, bb1.w);
        float* orow = out + (size_t)c * 64 + sl * 8;
        *(float4*)orow = o0;
        *(float4*)(orow + 4) = o1;
    }
}

// ---------------------------------------------------------------------------

extern "C" void kernel_launch(void* const* d_in, const int* in_sizes, int n_in,
                              void* d_out, int out_size, void* d_ws, size_t ws_size,
                              hipStream_t stream) {
    const float* x  = (const float*)d_in[0];
    const int*   ei = (const int*)  d_in[1];
    const float* W1 = (const float*)d_in[2];
    const float* b1 = (const float*)d_in[3];
    const float* W2 = (const float*)d_in[4];
    const float* b2 = (const float*)d_in[5];
    const float* W3 = (const float*)d_in[6];
    const float* b3 = (const float*)d_in[7];
    const float* W4 = (const float*)d_in[8];
    const float* b4 = (const float*)d_in[9];

    const int N = N_NODES, E = N_EDGES;

    char* p = (char*)d_ws;
    auto carve = [&](size_t bytes) {
        char* q = p;
        p += (bytes + 255) & ~(size_t)255;
        return (void*)q;
    };
    int*       offsets = (int*)      carve((size_t)(N + 1) * 4);
    int*       csr_src = (int*)      carve((size_t)E * 4);
    float*     dinv    = (float*)    carve((size_t)N * 4);
    int*       gcur    = (int*)      carve((size_t)NBUK * 4);
    unsigned*  arena   = (unsigned*) carve((size_t)NBUK * BCAP * 4);
    _Float16*  Wf1     = (_Float16*) carve((size_t)16 * 128 * 8 * 2);   // 32 KB
    _Float16*  Wf2     = (_Float16*) carve((size_t)16 * 128 * 8 * 2);
    _Float16*  Wf3     = (_Float16*) carve((size_t)16 * 128 * 8 * 2);
    _Float16*  Wf4     = (_Float16*) carve((size_t)16 * 64 * 8 * 2);    // 16 KB
    __half*    A1      = (__half*)   carve((size_t)N * 128 * 2);
    __half*    A2      = (__half*)   carve((size_t)N * 128 * 2);

    // ---- graph build + W conversion (3 dispatches) ----
    hipMemsetAsync(gcur, 0, (size_t)NBUK * 4, stream);
    p0_wfrag<<<540, 256, 0, stream>>>(ei, gcur, arena, E,
                                      W1, W2, W3, W4, Wf1, Wf2, Wf3, Wf4);
    build_graph<<<NBUK, 256, 0, stream>>>(arena, gcur, offsets, dinv, csr_src, N, E);

    // ---- layers (5 dispatches) ----
    const int nb64 = (N + 63) / 64;    // 782

    gemm_mfma_kernel<<<nb64, 256, 0, stream>>>(x, Wf1, dinv, A1, N);
    fused_agg_gemm<128><<<nb64, 512, 0, stream>>>((const _Float16*)A1, offsets, csr_src, dinv, b1, Wf2, A2, N);
    fused_agg_gemm<128><<<nb64, 512, 0, stream>>>((const _Float16*)A2, offsets, csr_src, dinv, b2, Wf3, A1, N);
    fused_agg_gemm<64><<<nb64, 512, 0, stream>>>((const _Float16*)A1, offsets, csr_src, dinv, b3, Wf4, A2, N);
    agg64_kernel<<<(N + 3) / 4, 256, 0, stream>>>((const _Float16*)A2, offsets, csr_src, dinv, b4, (float*)d_out, N);
}